// Round 10
// baseline (553.165 us; speedup 1.0000x reference)
//
#include <hip/hip_runtime.h>

// lossFunc: masked BCE-with-logits + sum/cnt^2 scalar loss + two masked passthrough arrays.
// Round 7: latency-regime fix. 12 independent float4 loads batched per super-iteration
// (192B/lane in flight, 4x round-6) so counted vmcnt waits on loads never sit behind
// stores in the FIFO; nontemporal stores keep the 268MB write stream from evicting
// L3-warm inputs. Transcendentals stay on v_exp_f32/v_log_f32.

__global__ __launch_bounds__(256) void bce_main_kernel(
    const float* __restrict__ pred,
    const float* __restrict__ labels,
    const int*   __restrict__ scores,
    float* __restrict__ bp,            // d_out + 1            (binary_preds)
    float* __restrict__ gt,            // d_out + 1 + N        (ground_truths)
    double* __restrict__ ws_sum,
    unsigned long long* __restrict__ ws_cnt,
    int nq)                            // number of float4 quads
{
    const float LOG2E = 1.4426950408889634f;
    const float LN2   = 0.6931471805599453f;

    const int T = gridDim.x * blockDim.x;
    const int t = blockIdx.x * blockDim.x + threadIdx.x;

    const float4* __restrict__ p4 = reinterpret_cast<const float4*>(pred);
    const float4* __restrict__ y4 = reinterpret_cast<const float4*>(labels);
    const int4*   __restrict__ s4 = reinterpret_cast<const int4*>(scores);

    double lsum = 0.0;
    unsigned int lcnt = 0;

    const int S = T * 4;               // quads per super-iteration
    int base = 0;

    for (; base + S <= nq; base += S) {
        // ---- issue all 12 loads back-to-back (independent, wave-coalesced) ----
        float4 p[4], y[4];
        int4   s[4];
        #pragma unroll
        for (int k = 0; k < 4; ++k) {
            const int q = base + k * T + t;
            p[k] = p4[q];
            y[k] = y4[q];
            s[k] = s4[q];
        }
        // ---- consume: compute + NT stores (stores are younger than all loads) ----
        #pragma unroll
        for (int k = 0; k < 4; ++k) {
            const int q  = base + k * T + t;
            const int e0 = q << 2;
            const float pv[4] = {p[k].x, p[k].y, p[k].z, p[k].w};
            const float yv[4] = {y[k].x, y[k].y, y[k].z, y[k].w};
            const int   sv[4] = {s[k].x, s[k].y, s[k].z, s[k].w};

            float qsum = 0.0f;
            #pragma unroll
            for (int j = 0; j < 4; ++j) {
                const bool  m  = (sv[j] == 1);
                const float x  = pv[j];
                const float yy = yv[j];
                __builtin_nontemporal_store(m ? x  : 0.0f, &bp[e0 + j]);
                __builtin_nontemporal_store(m ? yy : 0.0f, &gt[e0 + j]);

                const float a  = fabsf(x);
                const float u  = __builtin_amdgcn_exp2f(a * -LOG2E);    // v_exp_f32
                const float sp = __builtin_amdgcn_logf(1.0f + u) * LN2; // v_log_f32
                const float bce = fmaxf(x, 0.0f) - x * yy + sp;

                qsum += m ? bce : 0.0f;
                lcnt += (unsigned int)m;
            }
            lsum += (double)qsum;
        }
    }

    // ---- tail (nq % S != 0 — zero iterations for the bench shape) ----
    for (int q = base + t; q < nq; q += T) {
        const float4 p = p4[q];
        const float4 y = y4[q];
        const int4   s = s4[q];
        const int e0 = q << 2;
        const float pv[4] = {p.x, p.y, p.z, p.w};
        const float yv[4] = {y.x, y.y, y.z, y.w};
        const int   sv[4] = {s.x, s.y, s.z, s.w};
        float qsum = 0.0f;
        #pragma unroll
        for (int j = 0; j < 4; ++j) {
            const bool  m  = (sv[j] == 1);
            const float x  = pv[j];
            const float yy = yv[j];
            __builtin_nontemporal_store(m ? x  : 0.0f, &bp[e0 + j]);
            __builtin_nontemporal_store(m ? yy : 0.0f, &gt[e0 + j]);
            const float a  = fabsf(x);
            const float u  = __builtin_amdgcn_exp2f(a * -LOG2E);
            const float sp = __builtin_amdgcn_logf(1.0f + u) * LN2;
            const float bce = fmaxf(x, 0.0f) - x * yy + sp;
            qsum += m ? bce : 0.0f;
            lcnt += (unsigned int)m;
        }
        lsum += (double)qsum;
    }

    // ---- wave (64-lane) butterfly reduction ----
    #pragma unroll
    for (int off = 32; off > 0; off >>= 1) {
        lsum += __shfl_down(lsum, off, 64);
        lcnt += __shfl_down(lcnt, off, 64);
    }

    __shared__ double       ssum[4];
    __shared__ unsigned int scnt[4];
    const int wid  = threadIdx.x >> 6;
    const int lane = threadIdx.x & 63;
    if (lane == 0) { ssum[wid] = lsum; scnt[wid] = lcnt; }
    __syncthreads();

    if (threadIdx.x == 0) {
        const double bs = ssum[0] + ssum[1] + ssum[2] + ssum[3];
        const unsigned long long bc =
            (unsigned long long)scnt[0] + scnt[1] + scnt[2] + scnt[3];
        atomicAdd(ws_sum, bs);
        atomicAdd(ws_cnt, bc);
    }
}

__global__ void bce_finalize_kernel(const double* __restrict__ ws_sum,
                                    const unsigned long long* __restrict__ ws_cnt,
                                    float* __restrict__ out)
{
    const double c = (double)(*ws_cnt);
    out[0] = (float)(*ws_sum / (c * c));
}

extern "C" void kernel_launch(void* const* d_in, const int* in_sizes, int n_in,
                              void* d_out, int out_size, void* d_ws, size_t ws_size,
                              hipStream_t stream) {
    const float* pred   = (const float*)d_in[0];
    const float* labels = (const float*)d_in[1];
    const int*   scores = (const int*)d_in[2];
    float* out = (float*)d_out;

    const int N  = in_sizes[0];       // 8192*4096 = 33,554,432 (divisible by 4)
    const int nq = N >> 2;

    double* ws_sum             = (double*)d_ws;
    unsigned long long* ws_cnt = (unsigned long long*)((char*)d_ws + 8);

    // ws is poisoned 0xAA before every timed launch — zero the accumulators.
    (void)hipMemsetAsync(d_ws, 0, 16, stream);

    const int block = 256;
    const int grid  = 2048;           // 8 blocks/CU on 256 CUs; 4 super-iterations

    bce_main_kernel<<<grid, block, 0, stream>>>(
        pred, labels, scores,
        out + 1,            // binary_preds
        out + 1 + N,        // ground_truths
        ws_sum, ws_cnt, nq);

    bce_finalize_kernel<<<1, 1, 0, stream>>>(ws_sum, ws_cnt, out);
}

// Round 12
// 535.906 us; speedup vs baseline: 1.0322x; 1.0322x over previous
//
#include <hip/hip_runtime.h>

// lossFunc: masked BCE-with-logits + sum/cnt^2 scalar loss + two masked passthrough arrays.
// Round 11: aligned float4 output stores. Round-6's 8 scalar stores/quad were per-lane
// stride-16B scatters (16 line-touches each, 25% density). Output buffer is
// [loss][bp N][gt N]; output-quad j needs sources 4j-1..4j+2 — a one-element shift —
// obtained via __shfl_up from the neighboring lane (lane 0: 3 scalar boundary loads).
// Stores: 2 contiguous aligned dwordx4 per quad. NT stores reverted (round-10 regression).

__device__ __forceinline__ float bce_elem(float x, float yy) {
    const float LOG2E = 1.4426950408889634f;
    const float LN2   = 0.6931471805599453f;
    const float a  = fabsf(x);
    const float u  = __builtin_amdgcn_exp2f(a * -LOG2E);    // v_exp_f32
    const float sp = __builtin_amdgcn_logf(1.0f + u) * LN2; // v_log_f32
    return fmaxf(x, 0.0f) - x * yy + sp;
}

__global__ __launch_bounds__(256) void bce_main_kernel(
    const float* __restrict__ pred,
    const float* __restrict__ labels,
    const int*   __restrict__ scores,
    float* __restrict__ out,           // full output buffer (float4-aligned base)
    double* __restrict__ ws_sum,
    unsigned long long* __restrict__ ws_cnt,
    int NJ,                            // N/4 input quads (= bp-region output quads)
    int N)
{
    const int T    = gridDim.x * blockDim.x;
    const int t    = blockIdx.x * blockDim.x + threadIdx.x;
    const int lane = threadIdx.x & 63;

    const float4* __restrict__ p4 = reinterpret_cast<const float4*>(pred);
    const float4* __restrict__ y4 = reinterpret_cast<const float4*>(labels);
    const int4*   __restrict__ s4 = reinterpret_cast<const int4*>(scores);
    float4* __restrict__ o4 = reinterpret_cast<float4*>(out);

    double lsum = 0.0;
    unsigned int lcnt = 0;

    for (int j = t; j < NJ; j += T) {
        const float4 p = p4[j];
        const float4 y = y4[j];
        const int4   s = s4[j];

        const bool m0 = (s.x == 1), m1 = (s.y == 1), m2 = (s.z == 1), m3 = (s.w == 1);
        const float b0 = m0 ? p.x : 0.f, b1 = m1 ? p.y : 0.f,
                    b2 = m2 ? p.z : 0.f, b3 = m3 ? p.w : 0.f;
        const float g0 = m0 ? y.x : 0.f, g1 = m1 ? y.y : 0.f,
                    g2 = m2 ? y.z : 0.f, g3 = m3 ? y.w : 0.f;

        // shifted-by-one element from the previous quad (neighbor lane's elem 3)
        float pb = __shfl_up(b3, 1, 64);
        float pg = __shfl_up(g3, 1, 64);
        if (lane == 0) {
            if (j > 0) {
                const int sp_ = 4 * j - 1;          // previous quad's elem 3
                const bool mp = (scores[sp_] == 1);
                pb = mp ? pred[sp_]   : 0.f;
                pg = mp ? labels[sp_] : 0.f;
            } else {
                // out-quad 0 elem0 is the loss slot (finalize overwrites): write 0.
                pb = 0.f;
                // out-quad NJ elem0 is out[N] = bp[N-1] = mask[N-1] ? pred[N-1] : 0
                const bool ml = (scores[N - 1] == 1);
                pg = ml ? pred[N - 1] : 0.f;
                // global tail: out[2N] = gt[N-1]
                out[2 * N] = ml ? labels[N - 1] : 0.f;
            }
        }

        // two contiguous, 16B-aligned stores per quad
        o4[j]      = make_float4(pb, b0, b1, b2);   // bp-region quad
        o4[NJ + j] = make_float4(pg, g0, g1, g2);   // gt-region quad (same shift)

        // loss contribution (unshifted, each input quad exactly once)
        float qsum = 0.f;
        qsum += m0 ? bce_elem(p.x, y.x) : 0.f;
        qsum += m1 ? bce_elem(p.y, y.y) : 0.f;
        qsum += m2 ? bce_elem(p.z, y.z) : 0.f;
        qsum += m3 ? bce_elem(p.w, y.w) : 0.f;
        lcnt += (unsigned int)m0 + (unsigned int)m1 +
                (unsigned int)m2 + (unsigned int)m3;
        lsum += (double)qsum;
    }

    // wave (64-lane) butterfly reduction
    #pragma unroll
    for (int off = 32; off > 0; off >>= 1) {
        lsum += __shfl_down(lsum, off, 64);
        lcnt += __shfl_down(lcnt, off, 64);
    }

    __shared__ double       ssum[4];
    __shared__ unsigned int scnt[4];
    const int wid = threadIdx.x >> 6;
    if (lane == 0) { ssum[wid] = lsum; scnt[wid] = lcnt; }
    __syncthreads();

    if (threadIdx.x == 0) {
        const double bs = ssum[0] + ssum[1] + ssum[2] + ssum[3];
        const unsigned long long bc =
            (unsigned long long)scnt[0] + scnt[1] + scnt[2] + scnt[3];
        atomicAdd(ws_sum, bs);
        atomicAdd(ws_cnt, bc);
    }
}

__global__ void bce_finalize_kernel(const double* __restrict__ ws_sum,
                                    const unsigned long long* __restrict__ ws_cnt,
                                    float* __restrict__ out)
{
    const double c = (double)(*ws_cnt);
    out[0] = (float)(*ws_sum / (c * c));
}

extern "C" void kernel_launch(void* const* d_in, const int* in_sizes, int n_in,
                              void* d_out, int out_size, void* d_ws, size_t ws_size,
                              hipStream_t stream) {
    const float* pred   = (const float*)d_in[0];
    const float* labels = (const float*)d_in[1];
    const int*   scores = (const int*)d_in[2];
    float* out = (float*)d_out;

    const int N  = in_sizes[0];       // 8192*4096 = 33,554,432 (divisible by 4)
    const int NJ = N >> 2;

    double* ws_sum             = (double*)d_ws;
    unsigned long long* ws_cnt = (unsigned long long*)((char*)d_ws + 8);

    // ws is poisoned 0xAA before every timed launch — zero the accumulators.
    (void)hipMemsetAsync(d_ws, 0, 16, stream);

    const int block = 256;
    const int grid  = 2048;           // 8 blocks/CU on 256 CUs; 16 grid-stride iters

    bce_main_kernel<<<grid, block, 0, stream>>>(
        pred, labels, scores, out,
        ws_sum, ws_cnt, NJ, N);

    bce_finalize_kernel<<<1, 1, 0, stream>>>(ws_sum, ws_cnt, out);
}